// Round 1
// baseline (311.073 us; speedup 1.0000x reference)
//
#include <hip/hip_runtime.h>

#define BATCH 8
#define NPRED 25200
#define NCLS 80
#define ROWW 85
#define TOPKK 2048
#define MAXDET 300
#define CANDMAX 4096
#define NBUCKET 4096
#define CONF_T 0.2f
#define IOU_T 0.6f
#define CLS_OFF 4096.0f

// ---------------- K1: per-prediction best-class score + sortable key ----------------
__global__ __launch_bounds__(256) void k_score(
    const float* __restrict__ preds,
    unsigned long long* __restrict__ keys,
    unsigned char* __restrict__ cls8)
{
    int gid = blockIdx.x * 256 + threadIdx.x;
    if (gid >= BATCH * NPRED) return;
    const float* p = preds + (size_t)gid * ROWW;
    float obj = p[4];
    float best = -1.0f;
    int bc = 0;
    #pragma unroll 4
    for (int c = 0; c < NCLS; ++c) {
        float s = __fmul_rn(obj, p[5 + c]);
        if (s > best) { best = s; bc = c; }   // strict > keeps first (argmax semantics)
    }
    unsigned long long key = 0ull;
    if (best > CONF_T) {
        unsigned fb = __float_as_uint(best);          // positive float: bits monotonic
        unsigned i = (unsigned)(gid % NPRED);
        key = ((unsigned long long)fb << 32) | (0xFFFFFFFFu - i); // ties -> lower index first
    }
    keys[gid] = key;
    cls8[gid] = (unsigned char)bc;
}

// ---------------- K2: per-batch exact top-2048 (sorted desc) ----------------
// Histogram-select the candidate superset (monotonic bucketing => exact), compact,
// bitonic-sort 4096 u64 keys in LDS, emit top 2048 boxes/scores/classes.
__global__ __launch_bounds__(1024) void k_select(
    const float* __restrict__ preds,
    const unsigned long long* __restrict__ keys,
    const unsigned char* __restrict__ cls8,
    float* __restrict__ cbox,
    float* __restrict__ cscore,
    float* __restrict__ ccls)
{
    __shared__ unsigned int hist[NBUCKET];          // 16 KB
    __shared__ unsigned long long cand[CANDMAX];    // 32 KB
    __shared__ unsigned int partial[1024];          // 4 KB
    __shared__ int s_g;
    __shared__ int s_tb;
    __shared__ unsigned int s_cnt;

    const int b = blockIdx.x;
    const int t = threadIdx.x;
    const unsigned long long* bk = keys + (size_t)b * NPRED;

    for (int i = t; i < NBUCKET; i += 1024) hist[i] = 0u;
    __syncthreads();

    // histogram of valid scores (bucket = trunc(score*4096), monotonic)
    for (int i = t; i < NPRED; i += 1024) {
        unsigned long long k = bk[i];
        if (k) {
            float sc = __uint_as_float((unsigned)(k >> 32));
            int bkt = (int)(sc * (float)NBUCKET);
            if (bkt > NBUCKET - 1) bkt = NBUCKET - 1;
            atomicAdd(&hist[bkt], 1u);
        }
    }
    __syncthreads();

    // group sums of 4 buckets, then Hillis-Steele suffix scan over 1024 groups
    unsigned int ps = hist[4 * t] + hist[4 * t + 1] + hist[4 * t + 2] + hist[4 * t + 3];
    partial[t] = ps;
    __syncthreads();
    for (int off = 1; off < 1024; off <<= 1) {
        unsigned int v = partial[t] + ((t + off < 1024) ? partial[t + off] : 0u);
        __syncthreads();
        partial[t] = v;
        __syncthreads();
    }

    if (t == 0) s_g = -1;
    __syncthreads();
    // largest group g with suffix >= TOPKK
    if (partial[t] >= TOPKK && (t == 1023 || partial[t + 1] < TOPKK)) s_g = t;
    __syncthreads();

    if (t == 0) {
        int g = s_g;
        int tb;
        if (g < 0) {
            tb = 0;                          // fewer than TOPKK valid: take all
        } else {
            unsigned int base = (g < 1023) ? partial[g + 1] : 0u;
            unsigned int c3 = base + hist[4 * g + 3];
            unsigned int c2 = c3 + hist[4 * g + 2];
            unsigned int c1 = c2 + hist[4 * g + 1];
            if (c3 >= TOPKK) tb = 4 * g + 3;
            else if (c2 >= TOPKK) tb = 4 * g + 2;
            else if (c1 >= TOPKK) tb = 4 * g + 1;
            else tb = 4 * g;
        }
        s_tb = tb;
        s_cnt = 0u;
    }
    __syncthreads();
    const int tb = s_tb;

    for (int i = t; i < CANDMAX; i += 1024) cand[i] = 0ull;
    __syncthreads();

    // compact candidate superset (order irrelevant: keys are distinct, sort fixes it)
    for (int i = t; i < NPRED; i += 1024) {
        unsigned long long k = bk[i];
        if (k) {
            float sc = __uint_as_float((unsigned)(k >> 32));
            int bkt = (int)(sc * (float)NBUCKET);
            if (bkt > NBUCKET - 1) bkt = NBUCKET - 1;
            if (bkt >= tb) {
                unsigned int pos = atomicAdd(&s_cnt, 1u);
                if (pos < CANDMAX) cand[pos] = k;
            }
        }
    }
    __syncthreads();

    // bitonic sort, descending
    for (int k2 = 2; k2 <= CANDMAX; k2 <<= 1) {
        for (int j = k2 >> 1; j > 0; j >>= 1) {
            for (int i = t; i < CANDMAX; i += 1024) {
                int ixj = i ^ j;
                if (ixj > i) {
                    unsigned long long a = cand[i];
                    unsigned long long c = cand[ixj];
                    bool desc = ((i & k2) == 0);
                    bool sw = desc ? (a < c) : (a > c);
                    if (sw) { cand[i] = c; cand[ixj] = a; }
                }
            }
            __syncthreads();
        }
    }

    // emit top-2048: box (xyxy, no contraction), score, class
    for (int i = t; i < TOPKK; i += 1024) {
        unsigned long long k = cand[i];
        float x1 = 0.f, y1 = 0.f, x2 = 0.f, y2 = 0.f, sc = 0.f, cl = 0.f;
        if (k) {
            sc = __uint_as_float((unsigned)(k >> 32));
            unsigned idx = 0xFFFFFFFFu - (unsigned)(k & 0xFFFFFFFFu);
            const float* p = preds + ((size_t)b * NPRED + idx) * ROWW;
            float cx = p[0], cy = p[1], w = p[2], h = p[3];
            float hw = __fmul_rn(w, 0.5f);
            float hh = __fmul_rn(h, 0.5f);
            x1 = __fsub_rn(cx, hw);
            y1 = __fsub_rn(cy, hh);
            x2 = __fadd_rn(cx, hw);
            y2 = __fadd_rn(cy, hh);
            cl = (float)cls8[(size_t)b * NPRED + idx];
        }
        size_t o = (size_t)b * TOPKK + i;
        cbox[o * 4 + 0] = x1;
        cbox[o * 4 + 1] = y1;
        cbox[o * 4 + 2] = x2;
        cbox[o * 4 + 3] = y2;
        cscore[o] = sc;
        ccls[o] = cl;
    }
}

// ---------------- K3: per-batch greedy NMS with early stop at 300 kept ----------------
__global__ __launch_bounds__(64) void k_nms(
    const float* __restrict__ cbox,
    const float* __restrict__ cscore,
    const float* __restrict__ ccls,
    float* __restrict__ out)
{
    __shared__ float kb[MAXDET][4];   // kept OFFSET boxes
    const int b = blockIdx.x;
    const int lane = threadIdx.x;
    float* ob = out + (size_t)b * MAXDET * 6;
    const float* BB = cbox + (size_t)b * TOPKK * 4;
    const float* SS = cscore + (size_t)b * TOPKK;
    const float* CC = ccls + (size_t)b * TOPKK;

    int nk = 0;
    for (int i = 0; i < TOPKK; ++i) {
        float sc = SS[i];
        if (!(sc > CONF_T)) break;            // sorted desc: rest invalid
        float cl = CC[i];
        float off = __fmul_rn(cl, CLS_OFF);
        float bx1 = BB[i * 4 + 0], by1 = BB[i * 4 + 1];
        float bx2 = BB[i * 4 + 2], by2 = BB[i * 4 + 3];
        float x1 = __fadd_rn(bx1, off), y1 = __fadd_rn(by1, off);
        float x2 = __fadd_rn(bx2, off), y2 = __fadd_rn(by2, off);
        float areaA = __fmul_rn(__fsub_rn(x2, x1), __fsub_rn(y2, y1));

        bool sup = false;
        for (int j = lane; j < nk; j += 64) {
            float kx1 = kb[j][0], ky1 = kb[j][1], kx2 = kb[j][2], ky2 = kb[j][3];
            float lx = fmaxf(x1, kx1), ly = fmaxf(y1, ky1);
            float rx = fminf(x2, kx2), ry = fminf(y2, ky2);
            float iw = fmaxf(__fsub_rn(rx, lx), 0.0f);
            float ih = fmaxf(__fsub_rn(ry, ly), 0.0f);
            float inter = __fmul_rn(iw, ih);
            float areaB = __fmul_rn(__fsub_rn(kx2, kx1), __fsub_rn(ky2, ky1));
            float denom = __fadd_rn(__fsub_rn(__fadd_rn(areaA, areaB), inter), 1e-9f);
            float iou = __fdiv_rn(inter, denom);
            if (iou > IOU_T) sup = true;
        }
        unsigned long long bal = __ballot(sup);
        if (bal == 0ull) {
            if (lane == 0) {
                kb[nk][0] = x1; kb[nk][1] = y1; kb[nk][2] = x2; kb[nk][3] = y2;
                ob[nk * 6 + 0] = bx1;
                ob[nk * 6 + 1] = by1;
                ob[nk * 6 + 2] = bx2;
                ob[nk * 6 + 3] = by2;
                ob[nk * 6 + 4] = sc;
                ob[nk * 6 + 5] = cl;
            }
            nk++;
            __syncthreads();                  // kb visible to all lanes
            if (nk == MAXDET) break;
        }
    }
    __syncthreads();
    // zero remaining rows
    for (int x = nk * 6 + lane; x < MAXDET * 6; x += 64) ob[x] = 0.0f;
}

extern "C" void kernel_launch(void* const* d_in, const int* in_sizes, int n_in,
                              void* d_out, int out_size, void* d_ws, size_t ws_size,
                              hipStream_t stream) {
    const float* preds = (const float*)d_in[0];
    float* out = (float*)d_out;

    unsigned long long* keys = (unsigned long long*)d_ws;
    unsigned char* cls8 = (unsigned char*)(keys + (size_t)BATCH * NPRED);
    size_t off = (size_t)BATCH * NPRED * 8 + (size_t)BATCH * NPRED; // 1,814,400 (16-aligned)
    float* cbox = (float*)((char*)d_ws + off);
    float* cscore = cbox + (size_t)BATCH * TOPKK * 4;
    float* ccls = cscore + (size_t)BATCH * TOPKK;

    int total = BATCH * NPRED;
    int blocks = (total + 255) / 256;
    hipLaunchKernelGGL(k_score, dim3(blocks), dim3(256), 0, stream,
                       preds, keys, cls8);
    hipLaunchKernelGGL(k_select, dim3(BATCH), dim3(1024), 0, stream,
                       preds, keys, cls8, cbox, cscore, ccls);
    hipLaunchKernelGGL(k_nms, dim3(BATCH), dim3(64), 0, stream,
                       cbox, cscore, ccls, out);
}

// Round 2
// 214.524 us; speedup vs baseline: 1.4501x; 1.4501x over previous
//
#include <hip/hip_runtime.h>

#define BATCH 8
#define NPRED 25200
#define NCLS 80
#define ROWW 85
#define TOPKK 2048
#define MAXDET 300
#define CANDMAX 4096
#define NBUCKET 4096
#define CONF_T 0.2f
#define IOU_T 0.6f
#define CLS_OFF 4096.0f

// ---------------- K1: per-prediction best-class score + sortable key ----------------
__global__ __launch_bounds__(256) void k_score(
    const float* __restrict__ preds,
    unsigned long long* __restrict__ keys,
    unsigned char* __restrict__ cls8)
{
    int gid = blockIdx.x * 256 + threadIdx.x;
    if (gid >= BATCH * NPRED) return;
    const float* p = preds + (size_t)gid * ROWW;
    float obj = p[4];
    float best = -1.0f;
    int bc = 0;
    #pragma unroll 4
    for (int c = 0; c < NCLS; ++c) {
        float s = __fmul_rn(obj, p[5 + c]);
        if (s > best) { best = s; bc = c; }   // strict > keeps first (argmax semantics)
    }
    unsigned long long key = 0ull;
    if (best > CONF_T) {
        unsigned fb = __float_as_uint(best);          // positive float: bits monotonic
        unsigned i = (unsigned)(gid % NPRED);
        key = ((unsigned long long)fb << 32) | (0xFFFFFFFFu - i); // ties -> lower index first
    }
    keys[gid] = key;
    cls8[gid] = (unsigned char)bc;
}

// ---------------- K2: per-batch exact top-2048 (sorted desc) ----------------
__global__ __launch_bounds__(1024) void k_select(
    const float* __restrict__ preds,
    const unsigned long long* __restrict__ keys,
    const unsigned char* __restrict__ cls8,
    float* __restrict__ cbox,
    float* __restrict__ cscore,
    float* __restrict__ ccls)
{
    __shared__ unsigned int hist[NBUCKET];          // 16 KB
    __shared__ unsigned long long cand[CANDMAX];    // 32 KB
    __shared__ unsigned int partial[1024];          // 4 KB
    __shared__ int s_g;
    __shared__ int s_tb;
    __shared__ unsigned int s_cnt;

    const int b = blockIdx.x;
    const int t = threadIdx.x;
    const unsigned long long* bk = keys + (size_t)b * NPRED;

    for (int i = t; i < NBUCKET; i += 1024) hist[i] = 0u;
    __syncthreads();

    for (int i = t; i < NPRED; i += 1024) {
        unsigned long long k = bk[i];
        if (k) {
            float sc = __uint_as_float((unsigned)(k >> 32));
            int bkt = (int)(sc * (float)NBUCKET);
            if (bkt > NBUCKET - 1) bkt = NBUCKET - 1;
            atomicAdd(&hist[bkt], 1u);
        }
    }
    __syncthreads();

    unsigned int ps = hist[4 * t] + hist[4 * t + 1] + hist[4 * t + 2] + hist[4 * t + 3];
    partial[t] = ps;
    __syncthreads();
    for (int off = 1; off < 1024; off <<= 1) {
        unsigned int v = partial[t] + ((t + off < 1024) ? partial[t + off] : 0u);
        __syncthreads();
        partial[t] = v;
        __syncthreads();
    }

    if (t == 0) s_g = -1;
    __syncthreads();
    if (partial[t] >= TOPKK && (t == 1023 || partial[t + 1] < TOPKK)) s_g = t;
    __syncthreads();

    if (t == 0) {
        int g = s_g;
        int tb;
        if (g < 0) {
            tb = 0;
        } else {
            unsigned int base = (g < 1023) ? partial[g + 1] : 0u;
            unsigned int c3 = base + hist[4 * g + 3];
            unsigned int c2 = c3 + hist[4 * g + 2];
            unsigned int c1 = c2 + hist[4 * g + 1];
            if (c3 >= TOPKK) tb = 4 * g + 3;
            else if (c2 >= TOPKK) tb = 4 * g + 2;
            else if (c1 >= TOPKK) tb = 4 * g + 1;
            else tb = 4 * g;
        }
        s_tb = tb;
        s_cnt = 0u;
    }
    __syncthreads();
    const int tb = s_tb;

    for (int i = t; i < CANDMAX; i += 1024) cand[i] = 0ull;
    __syncthreads();

    for (int i = t; i < NPRED; i += 1024) {
        unsigned long long k = bk[i];
        if (k) {
            float sc = __uint_as_float((unsigned)(k >> 32));
            int bkt = (int)(sc * (float)NBUCKET);
            if (bkt > NBUCKET - 1) bkt = NBUCKET - 1;
            if (bkt >= tb) {
                unsigned int pos = atomicAdd(&s_cnt, 1u);
                if (pos < CANDMAX) cand[pos] = k;
            }
        }
    }
    __syncthreads();

    for (int k2 = 2; k2 <= CANDMAX; k2 <<= 1) {
        for (int j = k2 >> 1; j > 0; j >>= 1) {
            for (int i = t; i < CANDMAX; i += 1024) {
                int ixj = i ^ j;
                if (ixj > i) {
                    unsigned long long a = cand[i];
                    unsigned long long c = cand[ixj];
                    bool desc = ((i & k2) == 0);
                    bool sw = desc ? (a < c) : (a > c);
                    if (sw) { cand[i] = c; cand[ixj] = a; }
                }
            }
            __syncthreads();
        }
    }

    for (int i = t; i < TOPKK; i += 1024) {
        unsigned long long k = cand[i];
        float x1 = 0.f, y1 = 0.f, x2 = 0.f, y2 = 0.f, sc = 0.f, cl = 0.f;
        if (k) {
            sc = __uint_as_float((unsigned)(k >> 32));
            unsigned idx = 0xFFFFFFFFu - (unsigned)(k & 0xFFFFFFFFu);
            const float* p = preds + ((size_t)b * NPRED + idx) * ROWW;
            float cx = p[0], cy = p[1], w = p[2], h = p[3];
            float hw = __fmul_rn(w, 0.5f);
            float hh = __fmul_rn(h, 0.5f);
            x1 = __fsub_rn(cx, hw);
            y1 = __fsub_rn(cy, hh);
            x2 = __fadd_rn(cx, hw);
            y2 = __fadd_rn(cy, hh);
            cl = (float)cls8[(size_t)b * NPRED + idx];
        }
        size_t o = (size_t)b * TOPKK + i;
        cbox[o * 4 + 0] = x1;
        cbox[o * 4 + 1] = y1;
        cbox[o * 4 + 2] = x2;
        cbox[o * 4 + 3] = y2;
        cscore[o] = sc;
        ccls[o] = cl;
    }
}

// ---------------- K3: chunked wave-parallel greedy NMS, early stop at 300 ----------------
// One wave per batch. 64 candidates/chunk: lane-parallel IoU vs kept list (LDS),
// intra-chunk 64x64 masks via shfl, O(1) ballot resolve when no intra-chunk edges
// (common case), serial shfl fallback otherwise. Exact greedy semantics.
__global__ __launch_bounds__(64) void k_nms(
    const float* __restrict__ cbox,
    const float* __restrict__ cscore,
    const float* __restrict__ ccls,
    float* __restrict__ out)
{
    __shared__ float4 kb[MAXDET];     // kept OFFSET boxes
    const int b = blockIdx.x;
    const int lane = threadIdx.x;
    float* ob = out + (size_t)b * MAXDET * 6;
    const float4* BB4 = reinterpret_cast<const float4*>(cbox + (size_t)b * TOPKK * 4);
    const float* SS = cscore + (size_t)b * TOPKK;
    const float* CC = ccls + (size_t)b * TOPKK;

    const unsigned long long below =
        (lane == 0) ? 0ull : (~0ull >> (64 - lane));

    int nk = 0;
    for (int c = 0; c < TOPKK / 64; ++c) {
        int i = c * 64 + lane;
        float sc = SS[i];
        bool valid = sc > CONF_T;
        unsigned long long validmask = __ballot(valid);
        if (validmask == 0ull) break;

        float cl = CC[i];
        float4 bb = BB4[i];
        float off = __fmul_rn(cl, CLS_OFF);
        float x1 = __fadd_rn(bb.x, off), y1 = __fadd_rn(bb.y, off);
        float x2 = __fadd_rn(bb.z, off), y2 = __fadd_rn(bb.w, off);
        float areaA = __fmul_rn(__fsub_rn(x2, x1), __fsub_rn(y2, y1));

        // --- vs kept list (LDS broadcast reads) ---
        bool sup = false;
        for (int j = 0; j < nk; ++j) {
            float4 k4 = kb[j];
            float lx = fmaxf(x1, k4.x), ly = fmaxf(y1, k4.y);
            float rx = fminf(x2, k4.z), ry = fminf(y2, k4.w);
            float iw = fmaxf(__fsub_rn(rx, lx), 0.0f);
            float ih = fmaxf(__fsub_rn(ry, ly), 0.0f);
            float inter = __fmul_rn(iw, ih);
            float areaB = __fmul_rn(__fsub_rn(k4.z, k4.x), __fsub_rn(k4.w, k4.y));
            float denom = __fadd_rn(__fsub_rn(__fadd_rn(areaA, areaB), inter), 1e-9f);
            if (__fdiv_rn(inter, denom) > IOU_T) sup = true;
        }
        unsigned long long supprev = __ballot(sup);

        // --- intra-chunk 64x64 suppression masks via shfl ---
        unsigned sb_lo = 0u, sb_hi = 0u;
        for (int m = 0; m < 64; ++m) {
            float mx1 = __shfl(x1, m), my1 = __shfl(y1, m);
            float mx2 = __shfl(x2, m), my2 = __shfl(y2, m);
            float lx = fmaxf(x1, mx1), ly = fmaxf(y1, my1);
            float rx = fminf(x2, mx2), ry = fminf(y2, my2);
            float iw = fmaxf(__fsub_rn(rx, lx), 0.0f);
            float ih = fmaxf(__fsub_rn(ry, ly), 0.0f);
            float inter = __fmul_rn(iw, ih);
            float areaB = __fmul_rn(__fsub_rn(mx2, mx1), __fsub_rn(my2, my1));
            float denom = __fadd_rn(__fsub_rn(__fadd_rn(areaA, areaB), inter), 1e-9f);
            bool s = (m != lane) && (__fdiv_rn(inter, denom) > IOU_T);
            if (m < 32) sb_lo |= ((unsigned)s) << m;
            else        sb_hi |= ((unsigned)s) << (m - 32);
        }

        // --- ordered resolve ---
        unsigned long long eligible = validmask & ~supprev;
        unsigned long long mysb =
            (((unsigned long long)sb_hi << 32) | (unsigned long long)sb_lo);
        bool iselig = (eligible >> lane) & 1ull;
        unsigned long long edgeball =
            __ballot(iselig && ((mysb & eligible & below) != 0ull));

        unsigned long long keptm;
        if (edgeball == 0ull) {
            // fast path: no eligible candidate suppressed by an earlier eligible one
            int cap = MAXDET - nk;
            int rank = __popcll(eligible & below);
            keptm = __ballot(iselig && (rank < cap));
        } else {
            // slow path: serial greedy within the chunk (exact order)
            unsigned long long km = 0ull;
            int cnt = 0;
            int cap = MAXDET - nk;
            for (int m = 0; m < 64; ++m) {
                if (!((validmask >> m) & 1ull)) break;
                if (cnt >= cap) break;
                if ((supprev >> m) & 1ull) continue;
                unsigned mlo = (unsigned)__shfl((int)sb_lo, m);
                unsigned mhi = (unsigned)__shfl((int)sb_hi, m);
                unsigned long long supby =
                    (((unsigned long long)mhi << 32) | (unsigned long long)mlo);
                if (supby & km) continue;
                km |= 1ull << m;
                ++cnt;
            }
            keptm = km;
        }

        // --- append kept ---
        if ((keptm >> lane) & 1ull) {
            int pos = nk + __popcll(keptm & below);
            kb[pos] = make_float4(x1, y1, x2, y2);
            float* row = ob + pos * 6;
            row[0] = bb.x; row[1] = bb.y; row[2] = bb.z; row[3] = bb.w;
            row[4] = sc;   row[5] = cl;
        }
        nk += __popcll(keptm);
        __syncthreads();
        if (nk >= MAXDET) break;
        if (validmask != ~0ull) break;   // sorted: no more valid candidates
    }
    __syncthreads();
    for (int x = nk * 6 + lane; x < MAXDET * 6; x += 64) ob[x] = 0.0f;
}

extern "C" void kernel_launch(void* const* d_in, const int* in_sizes, int n_in,
                              void* d_out, int out_size, void* d_ws, size_t ws_size,
                              hipStream_t stream) {
    const float* preds = (const float*)d_in[0];
    float* out = (float*)d_out;

    unsigned long long* keys = (unsigned long long*)d_ws;
    unsigned char* cls8 = (unsigned char*)(keys + (size_t)BATCH * NPRED);
    size_t off = (size_t)BATCH * NPRED * 8 + (size_t)BATCH * NPRED; // 16-aligned
    float* cbox = (float*)((char*)d_ws + off);
    float* cscore = cbox + (size_t)BATCH * TOPKK * 4;
    float* ccls = cscore + (size_t)BATCH * TOPKK;

    int total = BATCH * NPRED;
    int blocks = (total + 255) / 256;
    hipLaunchKernelGGL(k_score, dim3(blocks), dim3(256), 0, stream,
                       preds, keys, cls8);
    hipLaunchKernelGGL(k_select, dim3(BATCH), dim3(1024), 0, stream,
                       preds, keys, cls8, cbox, cscore, ccls);
    hipLaunchKernelGGL(k_nms, dim3(BATCH), dim3(64), 0, stream,
                       cbox, cscore, ccls, out);
}

// Round 3
// 129.716 us; speedup vs baseline: 2.3981x; 1.6538x over previous
//
#include <hip/hip_runtime.h>

#define BATCH 8
#define NPRED 25200
#define NCLS 80
#define ROWW 85
#define TOPKK 2048
#define MAXDET 300
#define CANDMAX 4096
#define NBUCKET 4096
#define CONF_T 0.2f
#define IOU_T 0.6f
#define CLS_OFF 4096.0f

#define MASKN 384              // candidates with precomputed masks
#define MCH (MASKN / 64)       // 6 chunks
#define MSTR 9                 // padded u64 stride per row (bank-conflict-free)

// ---------------- K1: LDS-staged score/key (coalesced float4 global reads) ----------------
__global__ __launch_bounds__(64) void k_score(
    const float* __restrict__ preds,
    unsigned long long* __restrict__ keys,
    unsigned char* __restrict__ cls8)
{
    __shared__ float rows[64 * ROWW];   // 21760 B
    const int lane = threadIdx.x;
    const size_t rowbase = (size_t)blockIdx.x * 64;

    // contiguous float4 copy of this block's 64 rows (block base is 16B-aligned)
    const float4* src = reinterpret_cast<const float4*>(preds + rowbase * ROWW);
    float4* dst = reinterpret_cast<float4*>(rows);
    #pragma unroll
    for (int i = lane; i < 64 * ROWW / 4; i += 64) dst[i] = src[i];
    __syncthreads();

    const float* p = rows + lane * ROWW;
    float obj = p[4];
    float best = -1.0f;
    int bc = 0;
    #pragma unroll 8
    for (int c = 0; c < NCLS; ++c) {
        float s = __fmul_rn(obj, p[5 + c]);
        if (s > best) { best = s; bc = c; }   // strict > keeps first (argmax semantics)
    }
    size_t gid = rowbase + lane;
    unsigned long long key = 0ull;
    if (best > CONF_T) {
        unsigned fb = __float_as_uint(best);
        unsigned i = (unsigned)(gid % NPRED);
        key = ((unsigned long long)fb << 32) | (0xFFFFFFFFu - i);
    }
    keys[gid] = key;
    cls8[gid] = (unsigned char)bc;
}

// ---------------- K2: per-batch exact top-2048 (sorted desc) ----------------
__global__ __launch_bounds__(1024) void k_select(
    const float* __restrict__ preds,
    const unsigned long long* __restrict__ keys,
    const unsigned char* __restrict__ cls8,
    float* __restrict__ cbox,
    float* __restrict__ cscore,
    float* __restrict__ ccls)
{
    __shared__ unsigned int hist[NBUCKET];
    __shared__ unsigned long long cand[CANDMAX];
    __shared__ unsigned int partial[1024];
    __shared__ int s_g;
    __shared__ int s_tb;
    __shared__ unsigned int s_cnt;

    const int b = blockIdx.x;
    const int t = threadIdx.x;
    const unsigned long long* bk = keys + (size_t)b * NPRED;

    for (int i = t; i < NBUCKET; i += 1024) hist[i] = 0u;
    __syncthreads();

    for (int i = t; i < NPRED; i += 1024) {
        unsigned long long k = bk[i];
        if (k) {
            float sc = __uint_as_float((unsigned)(k >> 32));
            int bkt = (int)(sc * (float)NBUCKET);
            if (bkt > NBUCKET - 1) bkt = NBUCKET - 1;
            atomicAdd(&hist[bkt], 1u);
        }
    }
    __syncthreads();

    unsigned int ps = hist[4 * t] + hist[4 * t + 1] + hist[4 * t + 2] + hist[4 * t + 3];
    partial[t] = ps;
    __syncthreads();
    for (int off = 1; off < 1024; off <<= 1) {
        unsigned int v = partial[t] + ((t + off < 1024) ? partial[t + off] : 0u);
        __syncthreads();
        partial[t] = v;
        __syncthreads();
    }

    if (t == 0) s_g = -1;
    __syncthreads();
    if (partial[t] >= TOPKK && (t == 1023 || partial[t + 1] < TOPKK)) s_g = t;
    __syncthreads();

    if (t == 0) {
        int g = s_g;
        int tb;
        if (g < 0) {
            tb = 0;
        } else {
            unsigned int base = (g < 1023) ? partial[g + 1] : 0u;
            unsigned int c3 = base + hist[4 * g + 3];
            unsigned int c2 = c3 + hist[4 * g + 2];
            unsigned int c1 = c2 + hist[4 * g + 1];
            if (c3 >= TOPKK) tb = 4 * g + 3;
            else if (c2 >= TOPKK) tb = 4 * g + 2;
            else if (c1 >= TOPKK) tb = 4 * g + 1;
            else tb = 4 * g;
        }
        s_tb = tb;
        s_cnt = 0u;
    }
    __syncthreads();
    const int tb = s_tb;

    for (int i = t; i < CANDMAX; i += 1024) cand[i] = 0ull;
    __syncthreads();

    for (int i = t; i < NPRED; i += 1024) {
        unsigned long long k = bk[i];
        if (k) {
            float sc = __uint_as_float((unsigned)(k >> 32));
            int bkt = (int)(sc * (float)NBUCKET);
            if (bkt > NBUCKET - 1) bkt = NBUCKET - 1;
            if (bkt >= tb) {
                unsigned int pos = atomicAdd(&s_cnt, 1u);
                if (pos < CANDMAX) cand[pos] = k;
            }
        }
    }
    __syncthreads();

    for (int k2 = 2; k2 <= CANDMAX; k2 <<= 1) {
        for (int j = k2 >> 1; j > 0; j >>= 1) {
            for (int i = t; i < CANDMAX; i += 1024) {
                int ixj = i ^ j;
                if (ixj > i) {
                    unsigned long long a = cand[i];
                    unsigned long long c = cand[ixj];
                    bool desc = ((i & k2) == 0);
                    bool sw = desc ? (a < c) : (a > c);
                    if (sw) { cand[i] = c; cand[ixj] = a; }
                }
            }
            __syncthreads();
        }
    }

    for (int i = t; i < TOPKK; i += 1024) {
        unsigned long long k = cand[i];
        float x1 = 0.f, y1 = 0.f, x2 = 0.f, y2 = 0.f, sc = 0.f, cl = 0.f;
        if (k) {
            sc = __uint_as_float((unsigned)(k >> 32));
            unsigned idx = 0xFFFFFFFFu - (unsigned)(k & 0xFFFFFFFFu);
            const float* p = preds + ((size_t)b * NPRED + idx) * ROWW;
            float cx = p[0], cy = p[1], w = p[2], h = p[3];
            float hw = __fmul_rn(w, 0.5f);
            float hh = __fmul_rn(h, 0.5f);
            x1 = __fsub_rn(cx, hw);
            y1 = __fsub_rn(cy, hh);
            x2 = __fadd_rn(cx, hw);
            y2 = __fadd_rn(cy, hh);
            cl = (float)cls8[(size_t)b * NPRED + idx];
        }
        size_t o = (size_t)b * TOPKK + i;
        cbox[o * 4 + 0] = x1;
        cbox[o * 4 + 1] = y1;
        cbox[o * 4 + 2] = x2;
        cbox[o * 4 + 3] = y2;
        cscore[o] = sc;
        ccls[o] = cl;
    }
}

// ---------------- K3: fused mask-matrix NMS ----------------
// Per batch: 12 waves build the 384x384 suppression bit-matrix in LDS in
// parallel, then wave 0 resolves greedy NMS with pure bit ops (exact
// semantics). Fallback past candidate 384 uses on-the-fly IoU (correct,
// not triggered on typical data).
__global__ __launch_bounds__(1024) void k_nms(
    const float* __restrict__ cbox,
    const float* __restrict__ cscore,
    const float* __restrict__ ccls,
    float* __restrict__ out)
{
    __shared__ unsigned long long masks[MASKN * MSTR]; // 27648 B
    __shared__ float4 cbx[MASKN];                      // offset boxes
    __shared__ float carea[MASKN];
    __shared__ unsigned long long validw[MCH];
    __shared__ float4 kb[MAXDET];                      // kept offset boxes

    const int b = blockIdx.x;
    const int tid = threadIdx.x;
    const int lane = tid & 63;
    const int wave = tid >> 6;
    const float4* BB4 = reinterpret_cast<const float4*>(cbox + (size_t)b * TOPKK * 4);
    const float* SS = cscore + (size_t)b * TOPKK;
    const float* CC = ccls + (size_t)b * TOPKK;
    float* ob = out + (size_t)b * MAXDET * 6;

    // --- phase 1: stage offset boxes, areas, valid bits ---
    if (tid < MASKN) {
        float sc = SS[tid];
        float cl = CC[tid];
        float4 bb = BB4[tid];
        float off = __fmul_rn(cl, CLS_OFF);
        float4 obx = make_float4(__fadd_rn(bb.x, off), __fadd_rn(bb.y, off),
                                 __fadd_rn(bb.z, off), __fadd_rn(bb.w, off));
        cbx[tid] = obx;
        carea[tid] = __fmul_rn(__fsub_rn(obx.z, obx.x), __fsub_rn(obx.w, obx.y));
        unsigned long long vb = __ballot(sc > CONF_T);
        if (lane == 0) validw[wave] = vb;
    }
    __syncthreads();

    // --- phase 2: mask matrix. wave w: rows 64*(w>>1)+lane, cols 192*(w&1).. ---
    {
        const int rg = wave >> 1, chf = wave & 1;
        if (rg < MCH) {
            const int r = rg * 64 + lane;
            const float4 me = cbx[r];
            const float aA = carea[r];
            const int j0 = chf * 192;
            int wbase = r * MSTR + chf * 3;
            #pragma unroll
            for (int q = 0; q < 3; ++q) {
                unsigned long long acc = 0ull;
                const int base = j0 + q * 64;
                #pragma unroll 4
                for (int jj = 0; jj < 64; ++jj) {
                    const int j = base + jj;
                    float4 cb = cbx[j];
                    float lx = fmaxf(me.x, cb.x), ly = fmaxf(me.y, cb.y);
                    float rx = fminf(me.z, cb.z), ry = fminf(me.w, cb.w);
                    float iw = fmaxf(__fsub_rn(rx, lx), 0.0f);
                    float ih = fmaxf(__fsub_rn(ry, ly), 0.0f);
                    float inter = __fmul_rn(iw, ih);
                    float denom = __fadd_rn(__fsub_rn(__fadd_rn(aA, carea[j]), inter), 1e-9f);
                    bool s = (j != r) && (inter > __fmul_rn(IOU_T, denom));
                    acc |= ((unsigned long long)s) << jj;
                }
                masks[wbase + q] = acc;
            }
        }
    }
    __syncthreads();
    if (wave != 0) return;

    // --- phase 3: wave-0 greedy resolve over precomputed masks ---
    const unsigned long long below = (lane == 0) ? 0ull : (~0ull >> (64 - lane));
    unsigned long long S[MCH];
    #pragma unroll
    for (int w = 0; w < MCH; ++w) S[w] = 0ull;
    int nk = 0;
    bool done = false, allfull = true;

    #pragma unroll
    for (int c = 0; c < MCH; ++c) {
        if (done) break;
        unsigned long long vw = validw[c];
        unsigned long long eligible = vw & ~S[c];
        unsigned long long M = masks[(c * 64 + lane) * MSTR + c];
        bool elig = (eligible >> lane) & 1ull;
        if (eligible) {
            int cap = MAXDET - nk;
            unsigned long long edge =
                __ballot(elig && ((M & eligible & below) != 0ull));
            unsigned long long keptm;
            if (edge == 0ull) {
                int rank = __popcll(eligible & below);
                keptm = __ballot(elig && (rank < cap));
            } else {
                unsigned long long km = 0ull;
                int cnt = 0;
                for (int m = 0; m < 64 && cnt < cap; ++m) {
                    if (!((eligible >> m) & 1ull)) continue;
                    unsigned long long Mm = __shfl(M, m);
                    if (Mm & km) continue;
                    km |= 1ull << m;
                    ++cnt;
                }
                keptm = km;
            }
            if ((keptm >> lane) & 1ull) {
                int pos = nk + __popcll(keptm & below);
                int i = c * 64 + lane;
                float4 bb = BB4[i];
                kb[pos] = cbx[i];
                float* row = ob + pos * 6;
                row[0] = bb.x; row[1] = bb.y; row[2] = bb.z; row[3] = bb.w;
                row[4] = SS[i]; row[5] = CC[i];
            }
            nk += __popcll(keptm);
            if (nk >= MAXDET) {
                done = true;
            } else if (keptm) {
                #pragma unroll
                for (int w = 0; w < MCH; ++w) {
                    unsigned long long v = ((keptm >> lane) & 1ull)
                        ? masks[(c * 64 + lane) * MSTR + w] : 0ull;
                    v |= __shfl_xor(v, 1);  v |= __shfl_xor(v, 2);
                    v |= __shfl_xor(v, 4);  v |= __shfl_xor(v, 8);
                    v |= __shfl_xor(v, 16); v |= __shfl_xor(v, 32);
                    S[w] |= v;
                }
            }
        }
        if (vw != ~0ull) { allfull = false; break; }
    }

    // --- phase 4: fallback beyond MASKN (exact, rarely taken) ---
    if (!done && allfull && nk < MAXDET) {
        __threadfence_block();
        for (int c = MCH; c < TOPKK / 64; ++c) {
            int i = c * 64 + lane;
            float sc = SS[i];
            bool valid = sc > CONF_T;
            unsigned long long validmask = __ballot(valid);
            if (validmask == 0ull) break;

            float cl = CC[i];
            float4 bb = BB4[i];
            float off = __fmul_rn(cl, CLS_OFF);
            float x1 = __fadd_rn(bb.x, off), y1 = __fadd_rn(bb.y, off);
            float x2 = __fadd_rn(bb.z, off), y2 = __fadd_rn(bb.w, off);
            float areaA = __fmul_rn(__fsub_rn(x2, x1), __fsub_rn(y2, y1));

            bool sup = false;
            for (int j = 0; j < nk; ++j) {
                float4 k4 = kb[j];
                float lx = fmaxf(x1, k4.x), ly = fmaxf(y1, k4.y);
                float rx = fminf(x2, k4.z), ry = fminf(y2, k4.w);
                float iw = fmaxf(__fsub_rn(rx, lx), 0.0f);
                float ih = fmaxf(__fsub_rn(ry, ly), 0.0f);
                float inter = __fmul_rn(iw, ih);
                float areaB = __fmul_rn(__fsub_rn(k4.z, k4.x), __fsub_rn(k4.w, k4.y));
                float denom = __fadd_rn(__fsub_rn(__fadd_rn(areaA, areaB), inter), 1e-9f);
                if (inter > __fmul_rn(IOU_T, denom)) sup = true;
            }
            unsigned long long supprev = __ballot(sup);

            unsigned sb_lo = 0u, sb_hi = 0u;
            for (int m = 0; m < 64; ++m) {
                float mx1 = __shfl(x1, m), my1 = __shfl(y1, m);
                float mx2 = __shfl(x2, m), my2 = __shfl(y2, m);
                float lx = fmaxf(x1, mx1), ly = fmaxf(y1, my1);
                float rx = fminf(x2, mx2), ry = fminf(y2, my2);
                float iw = fmaxf(__fsub_rn(rx, lx), 0.0f);
                float ih = fmaxf(__fsub_rn(ry, ly), 0.0f);
                float inter = __fmul_rn(iw, ih);
                float areaB = __fmul_rn(__fsub_rn(mx2, mx1), __fsub_rn(my2, my1));
                float denom = __fadd_rn(__fsub_rn(__fadd_rn(areaA, areaB), inter), 1e-9f);
                bool s = (m != lane) && (inter > __fmul_rn(IOU_T, denom));
                if (m < 32) sb_lo |= ((unsigned)s) << m;
                else        sb_hi |= ((unsigned)s) << (m - 32);
            }

            unsigned long long eligible = validmask & ~supprev;
            unsigned long long mysb =
                (((unsigned long long)sb_hi << 32) | (unsigned long long)sb_lo);
            bool iselig = (eligible >> lane) & 1ull;
            unsigned long long edgeball =
                __ballot(iselig && ((mysb & eligible & below) != 0ull));

            unsigned long long keptm;
            int cap = MAXDET - nk;
            if (edgeball == 0ull) {
                int rank = __popcll(eligible & below);
                keptm = __ballot(iselig && (rank < cap));
            } else {
                unsigned long long km = 0ull;
                int cnt = 0;
                for (int m = 0; m < 64 && cnt < cap; ++m) {
                    if (!((validmask >> m) & 1ull)) break;
                    if ((supprev >> m) & 1ull) continue;
                    unsigned mlo = (unsigned)__shfl((int)sb_lo, m);
                    unsigned mhi = (unsigned)__shfl((int)sb_hi, m);
                    unsigned long long supby =
                        (((unsigned long long)mhi << 32) | (unsigned long long)mlo);
                    if (supby & km) continue;
                    km |= 1ull << m;
                    ++cnt;
                }
                keptm = km;
            }

            if ((keptm >> lane) & 1ull) {
                int pos = nk + __popcll(keptm & below);
                kb[pos] = make_float4(x1, y1, x2, y2);
                float* row = ob + pos * 6;
                row[0] = bb.x; row[1] = bb.y; row[2] = bb.z; row[3] = bb.w;
                row[4] = sc;   row[5] = cl;
            }
            __threadfence_block();
            nk += __popcll(keptm);
            if (nk >= MAXDET) break;
            if (validmask != ~0ull) break;
        }
    }

    for (int x = nk * 6 + lane; x < MAXDET * 6; x += 64) ob[x] = 0.0f;
}

extern "C" void kernel_launch(void* const* d_in, const int* in_sizes, int n_in,
                              void* d_out, int out_size, void* d_ws, size_t ws_size,
                              hipStream_t stream) {
    const float* preds = (const float*)d_in[0];
    float* out = (float*)d_out;

    unsigned long long* keys = (unsigned long long*)d_ws;
    unsigned char* cls8 = (unsigned char*)(keys + (size_t)BATCH * NPRED);
    size_t off = (size_t)BATCH * NPRED * 8 + (size_t)BATCH * NPRED; // 16-aligned
    float* cbox = (float*)((char*)d_ws + off);
    float* cscore = cbox + (size_t)BATCH * TOPKK * 4;
    float* ccls = cscore + (size_t)BATCH * TOPKK;

    hipLaunchKernelGGL(k_score, dim3(BATCH * NPRED / 64), dim3(64), 0, stream,
                       preds, keys, cls8);
    hipLaunchKernelGGL(k_select, dim3(BATCH), dim3(1024), 0, stream,
                       preds, keys, cls8, cbox, cscore, ccls);
    hipLaunchKernelGGL(k_nms, dim3(BATCH), dim3(1024), 0, stream,
                       cbox, cscore, ccls, out);
}

// Round 4
// 71.635 us; speedup vs baseline: 4.3425x; 1.8108x over previous
//
#include <hip/hip_runtime.h>

#define BATCH 8
#define NPRED 25200
#define NCLS 80
#define ROWW 85
#define TOPKK 2048
#define MAXDET 300
#define CANDMAX 4096
#define NBUCKET 4096
#define CONF_T 0.2f
#define IOU_T 0.6f
#define CLS_OFF 4096.0f

#define MASKN 384              // candidates with precomputed masks
#define MCH (MASKN / 64)       // 6 chunks
#define MW 13                  // u32 stride per mask row (gcd(13,32)=1: conflict-free)

__device__ __forceinline__ int bucket_of_key(unsigned long long k) {
    float sc = __uint_as_float((unsigned)(k >> 32));
    int bkt = (int)(sc * (float)NBUCKET);
    return (bkt > NBUCKET - 1) ? (NBUCKET - 1) : bkt;
}

// ---------------- K1: LDS-staged score/key (coalesced float4 global reads) ----------------
__global__ __launch_bounds__(64) void k_score(
    const float* __restrict__ preds,
    unsigned long long* __restrict__ keys,
    unsigned char* __restrict__ cls8)
{
    __shared__ float rows[64 * ROWW];   // 21760 B
    const int lane = threadIdx.x;
    const size_t rowbase = (size_t)blockIdx.x * 64;

    const float4* src = reinterpret_cast<const float4*>(preds + rowbase * ROWW);
    float4* dst = reinterpret_cast<float4*>(rows);
    #pragma unroll
    for (int i = lane; i < 64 * ROWW / 4; i += 64) dst[i] = src[i];
    __syncthreads();

    const float* p = rows + lane * ROWW;
    float obj = p[4];
    float best = -1.0f;
    int bc = 0;
    #pragma unroll 8
    for (int c = 0; c < NCLS; ++c) {
        float s = __fmul_rn(obj, p[5 + c]);
        if (s > best) { best = s; bc = c; }   // strict > keeps first (argmax semantics)
    }
    size_t gid = rowbase + lane;
    unsigned long long key = 0ull;
    if (best > CONF_T) {
        unsigned fb = __float_as_uint(best);
        unsigned i = (unsigned)(gid % NPRED);
        key = ((unsigned long long)fb << 32) | (0xFFFFFFFFu - i);
    }
    keys[gid] = key;
    cls8[gid] = (unsigned char)bc;
}

// ---------------- K2: per-batch exact top-2048 via bucket-rank (no bitonic) ----------------
// hist -> per-bucket start offsets (desc order) -> bucket-grouped compaction ->
// exact rank = bstart[bucket] + within-bucket comparison count -> direct emit.
__global__ __launch_bounds__(1024) void k_select(
    const float* __restrict__ preds,
    const unsigned long long* __restrict__ keys,
    const unsigned char* __restrict__ cls8,
    float* __restrict__ cbox,
    float* __restrict__ cscore,
    float* __restrict__ ccls)
{
    __shared__ unsigned int hist[NBUCKET];            // 16 KB
    __shared__ unsigned int bstart[NBUCKET];          // 16 KB
    __shared__ unsigned int bfill[NBUCKET];           // 16 KB
    __shared__ unsigned long long cand[CANDMAX];      // 32 KB (bucket-grouped keys)
    __shared__ unsigned int partial[1024];            // 4 KB
    __shared__ int s_tb;
    __shared__ unsigned int s_stored;

    const int b = blockIdx.x;
    const int t = threadIdx.x;
    const unsigned long long* bk = keys + (size_t)b * NPRED;

    for (int i = t; i < NBUCKET; i += 1024) { hist[i] = 0u; bfill[i] = 0u; }
    if (t == 0) s_tb = 0;
    __syncthreads();

    // --- histogram ---
    for (int i = t; i < NPRED; i += 1024) {
        unsigned long long k = bk[i];
        if (k) atomicAdd(&hist[bucket_of_key(k)], 1u);
    }
    __syncthreads();

    // --- group sums (4 buckets/thread) + Hillis-Steele suffix scan ---
    unsigned h0 = hist[4 * t], h1 = hist[4 * t + 1], h2 = hist[4 * t + 2], h3 = hist[4 * t + 3];
    partial[t] = h0 + h1 + h2 + h3;
    __syncthreads();
    for (int off = 1; off < 1024; off <<= 1) {
        unsigned int v = partial[t] + ((t + off < 1024) ? partial[t + off] : 0u);
        __syncthreads();
        partial[t] = v;
        __syncthreads();
    }
    // partial[t] = sum of buckets >= 4t

    // per-bucket desc start (= #keys in buckets strictly greater)
    unsigned snext = (t < 1023) ? partial[t + 1] : 0u;
    unsigned b3 = snext;
    unsigned b2 = b3 + h3;
    unsigned b1 = b2 + h2;
    unsigned b0 = b1 + h1;
    bstart[4 * t + 3] = b3;
    bstart[4 * t + 2] = b2;
    bstart[4 * t + 1] = b1;
    bstart[4 * t + 0] = b0;

    // threshold bucket tb: unique k with count(>=k) >= TOPKK and count(>k) < TOPKK
    {
        unsigned cnt3 = b3 + h3, cnt2 = b2 + h2, cnt1 = b1 + h1, cnt0 = b0 + h0;
        if (cnt3 >= TOPKK && b3 < TOPKK) s_tb = 4 * t + 3;
        if (cnt2 >= TOPKK && b2 < TOPKK) s_tb = 4 * t + 2;
        if (cnt1 >= TOPKK && b1 < TOPKK) s_tb = 4 * t + 1;
        if (cnt0 >= TOPKK && b0 < TOPKK) s_tb = 4 * t + 0;
    }
    __syncthreads();
    const int tb = s_tb;
    if (t == 0) {
        unsigned cnt = bstart[tb] + hist[tb];
        s_stored = (cnt < (unsigned)CANDMAX) ? cnt : (unsigned)CANDMAX;
    }

    // --- bucket-grouped compaction ---
    for (int i = t; i < NPRED; i += 1024) {
        unsigned long long k = bk[i];
        if (k) {
            int bkt = bucket_of_key(k);
            if (bkt >= tb) {
                unsigned slot = bstart[bkt] + atomicAdd(&bfill[bkt], 1u);
                if (slot < CANDMAX) cand[slot] = k;
            }
        }
    }
    __syncthreads();
    const unsigned stored = s_stored;

    // --- zero-fill tail ranks (only when fewer than TOPKK candidates) ---
    for (unsigned i = stored + t; i < TOPKK; i += 1024) {
        size_t o = (size_t)b * TOPKK + i;
        cbox[o * 4 + 0] = 0.f; cbox[o * 4 + 1] = 0.f;
        cbox[o * 4 + 2] = 0.f; cbox[o * 4 + 3] = 0.f;
        cscore[o] = 0.f; ccls[o] = 0.f;
    }

    // --- exact rank + direct emit ---
    for (unsigned i = t; i < stored; i += 1024) {
        unsigned long long k = cand[i];
        int bkt = bucket_of_key(k);
        unsigned base = bstart[bkt];
        unsigned end = base + hist[bkt];
        if (end > stored) end = stored;
        unsigned r = base;
        for (unsigned j = base; j < end; ++j) r += (cand[j] > k) ? 1u : 0u;
        if (r < TOPKK) {
            float sc = __uint_as_float((unsigned)(k >> 32));
            unsigned idx = 0xFFFFFFFFu - (unsigned)(k & 0xFFFFFFFFu);
            const float* p = preds + ((size_t)b * NPRED + idx) * ROWW;
            float cx = p[0], cy = p[1], w = p[2], h = p[3];
            float hw = __fmul_rn(w, 0.5f);
            float hh = __fmul_rn(h, 0.5f);
            size_t o = (size_t)b * TOPKK + r;
            cbox[o * 4 + 0] = __fsub_rn(cx, hw);
            cbox[o * 4 + 1] = __fsub_rn(cy, hh);
            cbox[o * 4 + 2] = __fadd_rn(cx, hw);
            cbox[o * 4 + 3] = __fadd_rn(cy, hh);
            cscore[o] = sc;
            ccls[o] = (float)cls8[(size_t)b * NPRED + idx];
        }
    }
}

// ---------------- K3: fused mask-matrix NMS ----------------
// 12 waves build the 384x384 suppression bit-matrix (6 rows/lane x 32-col slice
// per wave: each broadcast column read feeds 6 IoUs), wave 0 resolves greedy
// NMS with bit ops. Fallback past candidate 384 is exact on-the-fly.
__global__ __launch_bounds__(1024) void k_nms(
    const float* __restrict__ cbox,
    const float* __restrict__ cscore,
    const float* __restrict__ ccls,
    float* __restrict__ out)
{
    __shared__ unsigned int masks32[MASKN * MW];       // 19968 B
    __shared__ float4 cbx[MASKN];                      // offset boxes
    __shared__ float carea[MASKN];
    __shared__ unsigned long long validw[MCH];
    __shared__ float4 kb[MAXDET];                      // kept offset boxes

    const int b = blockIdx.x;
    const int tid = threadIdx.x;
    const int lane = tid & 63;
    const int wave = tid >> 6;
    const float4* BB4 = reinterpret_cast<const float4*>(cbox + (size_t)b * TOPKK * 4);
    const float* SS = cscore + (size_t)b * TOPKK;
    const float* CC = ccls + (size_t)b * TOPKK;
    float* ob = out + (size_t)b * MAXDET * 6;

    // --- phase 1: stage offset boxes, areas, valid bits ---
    if (tid < MASKN) {
        float sc = SS[tid];
        float cl = CC[tid];
        float4 bb = BB4[tid];
        float off = __fmul_rn(cl, CLS_OFF);
        float4 obx = make_float4(__fadd_rn(bb.x, off), __fadd_rn(bb.y, off),
                                 __fadd_rn(bb.z, off), __fadd_rn(bb.w, off));
        cbx[tid] = obx;
        carea[tid] = __fmul_rn(__fsub_rn(obx.z, obx.x), __fsub_rn(obx.w, obx.y));
        unsigned long long vb = __ballot(sc > CONF_T);
        if (lane == 0) validw[wave] = vb;
    }
    __syncthreads();

    // --- phase 2: mask matrix; wave w handles cols [32w,32w+32), all 384 rows ---
    if (wave < 12) {
        float4 me[MCH];
        float aA[MCH];
        #pragma unroll
        for (int q = 0; q < MCH; ++q) {
            me[q] = cbx[q * 64 + lane];
            aA[q] = carea[q * 64 + lane];
        }
        unsigned acc[MCH] = {0u, 0u, 0u, 0u, 0u, 0u};
        const int j0 = wave * 32;
        for (int jj = 0; jj < 32; ++jj) {
            const int j = j0 + jj;
            float4 cb = cbx[j];
            float aB = carea[j];
            #pragma unroll
            for (int q = 0; q < MCH; ++q) {
                float lx = fmaxf(me[q].x, cb.x), ly = fmaxf(me[q].y, cb.y);
                float rx = fminf(me[q].z, cb.z), ry = fminf(me[q].w, cb.w);
                float iw = fmaxf(__fsub_rn(rx, lx), 0.0f);
                float ih = fmaxf(__fsub_rn(ry, ly), 0.0f);
                float inter = __fmul_rn(iw, ih);
                float denom = __fadd_rn(__fsub_rn(__fadd_rn(aA[q], aB), inter), 1e-9f);
                bool s = inter > __fmul_rn(IOU_T, denom);
                acc[q] |= ((unsigned)s) << jj;
            }
        }
        #pragma unroll
        for (int q = 0; q < MCH; ++q) {
            int r = q * 64 + lane;
            unsigned a = acc[q];
            if ((r >> 5) == wave) a &= ~(1u << (r & 31));   // never self-suppress
            masks32[r * MW + wave] = a;
        }
    }
    __syncthreads();
    if (wave != 0) return;

    // --- phase 3: wave-0 greedy resolve over precomputed masks ---
    const unsigned long long below = (lane == 0) ? 0ull : (~0ull >> (64 - lane));
    unsigned long long S[MCH];
    #pragma unroll
    for (int w = 0; w < MCH; ++w) S[w] = 0ull;
    int nk = 0;
    bool done = false, allfull = true;

    #pragma unroll
    for (int c = 0; c < MCH; ++c) {
        if (done) break;
        unsigned long long vw = validw[c];
        unsigned long long eligible = vw & ~S[c];
        const int rbase = (c * 64 + lane) * MW;
        unsigned long long M =
            ((unsigned long long)masks32[rbase + 2 * c + 1] << 32) |
            (unsigned long long)masks32[rbase + 2 * c];
        bool elig = (eligible >> lane) & 1ull;
        if (eligible) {
            int cap = MAXDET - nk;
            unsigned long long edge =
                __ballot(elig && ((M & eligible & below) != 0ull));
            unsigned long long keptm;
            if (edge == 0ull) {
                int rank = __popcll(eligible & below);
                keptm = __ballot(elig && (rank < cap));
            } else {
                unsigned long long km = 0ull;
                int cnt = 0;
                for (int m = 0; m < 64 && cnt < cap; ++m) {
                    if (!((eligible >> m) & 1ull)) continue;
                    unsigned long long Mm = __shfl(M, m);
                    if (Mm & km) continue;
                    km |= 1ull << m;
                    ++cnt;
                }
                keptm = km;
            }
            if ((keptm >> lane) & 1ull) {
                int pos = nk + __popcll(keptm & below);
                int i = c * 64 + lane;
                float4 bb = BB4[i];
                kb[pos] = cbx[i];
                float* row = ob + pos * 6;
                row[0] = bb.x; row[1] = bb.y; row[2] = bb.z; row[3] = bb.w;
                row[4] = SS[i]; row[5] = CC[i];
            }
            nk += __popcll(keptm);
            if (nk >= MAXDET) {
                done = true;
            } else if (keptm) {
                #pragma unroll
                for (int w = 0; w < MCH; ++w) {
                    unsigned long long v = ((keptm >> lane) & 1ull)
                        ? (((unsigned long long)masks32[rbase + 2 * w + 1] << 32) |
                           (unsigned long long)masks32[rbase + 2 * w])
                        : 0ull;
                    v |= __shfl_xor(v, 1);  v |= __shfl_xor(v, 2);
                    v |= __shfl_xor(v, 4);  v |= __shfl_xor(v, 8);
                    v |= __shfl_xor(v, 16); v |= __shfl_xor(v, 32);
                    S[w] |= v;
                }
            }
        }
        if (vw != ~0ull) { allfull = false; break; }
    }

    // --- phase 4: fallback beyond MASKN (exact, rarely taken) ---
    if (!done && allfull && nk < MAXDET) {
        __threadfence_block();
        for (int c = MCH; c < TOPKK / 64; ++c) {
            int i = c * 64 + lane;
            float sc = SS[i];
            bool valid = sc > CONF_T;
            unsigned long long validmask = __ballot(valid);
            if (validmask == 0ull) break;

            float cl = CC[i];
            float4 bb = BB4[i];
            float off = __fmul_rn(cl, CLS_OFF);
            float x1 = __fadd_rn(bb.x, off), y1 = __fadd_rn(bb.y, off);
            float x2 = __fadd_rn(bb.z, off), y2 = __fadd_rn(bb.w, off);
            float areaA = __fmul_rn(__fsub_rn(x2, x1), __fsub_rn(y2, y1));

            bool sup = false;
            for (int j = 0; j < nk; ++j) {
                float4 k4 = kb[j];
                float lx = fmaxf(x1, k4.x), ly = fmaxf(y1, k4.y);
                float rx = fminf(x2, k4.z), ry = fminf(y2, k4.w);
                float iw = fmaxf(__fsub_rn(rx, lx), 0.0f);
                float ih = fmaxf(__fsub_rn(ry, ly), 0.0f);
                float inter = __fmul_rn(iw, ih);
                float areaB = __fmul_rn(__fsub_rn(k4.z, k4.x), __fsub_rn(k4.w, k4.y));
                float denom = __fadd_rn(__fsub_rn(__fadd_rn(areaA, areaB), inter), 1e-9f);
                if (inter > __fmul_rn(IOU_T, denom)) sup = true;
            }
            unsigned long long supprev = __ballot(sup);

            unsigned sb_lo = 0u, sb_hi = 0u;
            for (int m = 0; m < 64; ++m) {
                float mx1 = __shfl(x1, m), my1 = __shfl(y1, m);
                float mx2 = __shfl(x2, m), my2 = __shfl(y2, m);
                float lx = fmaxf(x1, mx1), ly = fmaxf(y1, my1);
                float rx = fminf(x2, mx2), ry = fminf(y2, my2);
                float iw = fmaxf(__fsub_rn(rx, lx), 0.0f);
                float ih = fmaxf(__fsub_rn(ry, ly), 0.0f);
                float inter = __fmul_rn(iw, ih);
                float areaB = __fmul_rn(__fsub_rn(mx2, mx1), __fsub_rn(my2, my1));
                float denom = __fadd_rn(__fsub_rn(__fadd_rn(areaA, areaB), inter), 1e-9f);
                bool s = (m != lane) && (inter > __fmul_rn(IOU_T, denom));
                if (m < 32) sb_lo |= ((unsigned)s) << m;
                else        sb_hi |= ((unsigned)s) << (m - 32);
            }

            unsigned long long eligible = validmask & ~supprev;
            unsigned long long mysb =
                (((unsigned long long)sb_hi << 32) | (unsigned long long)sb_lo);
            bool iselig = (eligible >> lane) & 1ull;
            unsigned long long edgeball =
                __ballot(iselig && ((mysb & eligible & below) != 0ull));

            unsigned long long keptm;
            int cap = MAXDET - nk;
            if (edgeball == 0ull) {
                int rank = __popcll(eligible & below);
                keptm = __ballot(iselig && (rank < cap));
            } else {
                unsigned long long km = 0ull;
                int cnt = 0;
                for (int m = 0; m < 64 && cnt < cap; ++m) {
                    if (!((validmask >> m) & 1ull)) break;
                    if ((supprev >> m) & 1ull) continue;
                    unsigned mlo = (unsigned)__shfl((int)sb_lo, m);
                    unsigned mhi = (unsigned)__shfl((int)sb_hi, m);
                    unsigned long long supby =
                        (((unsigned long long)mhi << 32) | (unsigned long long)mlo);
                    if (supby & km) continue;
                    km |= 1ull << m;
                    ++cnt;
                }
                keptm = km;
            }

            if ((keptm >> lane) & 1ull) {
                int pos = nk + __popcll(keptm & below);
                kb[pos] = make_float4(x1, y1, x2, y2);
                float* row = ob + pos * 6;
                row[0] = bb.x; row[1] = bb.y; row[2] = bb.z; row[3] = bb.w;
                row[4] = sc;   row[5] = cl;
            }
            __threadfence_block();
            nk += __popcll(keptm);
            if (nk >= MAXDET) break;
            if (validmask != ~0ull) break;
        }
    }

    for (int x = nk * 6 + lane; x < MAXDET * 6; x += 64) ob[x] = 0.0f;
}

extern "C" void kernel_launch(void* const* d_in, const int* in_sizes, int n_in,
                              void* d_out, int out_size, void* d_ws, size_t ws_size,
                              hipStream_t stream) {
    const float* preds = (const float*)d_in[0];
    float* out = (float*)d_out;

    unsigned long long* keys = (unsigned long long*)d_ws;
    unsigned char* cls8 = (unsigned char*)(keys + (size_t)BATCH * NPRED);
    size_t off = (size_t)BATCH * NPRED * 8 + (size_t)BATCH * NPRED; // 16-aligned
    float* cbox = (float*)((char*)d_ws + off);
    float* cscore = cbox + (size_t)BATCH * TOPKK * 4;
    float* ccls = cscore + (size_t)BATCH * TOPKK;

    hipLaunchKernelGGL(k_score, dim3(BATCH * NPRED / 64), dim3(64), 0, stream,
                       preds, keys, cls8);
    hipLaunchKernelGGL(k_select, dim3(BATCH), dim3(1024), 0, stream,
                       preds, keys, cls8, cbox, cscore, ccls);
    hipLaunchKernelGGL(k_nms, dim3(BATCH), dim3(1024), 0, stream,
                       cbox, cscore, ccls, out);
}